// Round 4
// baseline (262.914 us; speedup 1.0000x reference)
//
#include <hip/hip_runtime.h>
#include <math.h>

// B=8, C=64, H=512, W=512, K=8, HID=64, nh=nw=64, L=4096
//
//  A) mlp_precompute: pk[L][64], pb[L] into d_ws.
//  B) afpm_main: persistent-pipelined. Grid = 512 blocks = (b:8, ph:64),
//     exactly 2 blocks/CU. Block loops over 16 patch-groups (4 patches each),
//     prefetching group g+1's pixels into the alternate register buffer before
//     consuming group g -> the __syncthreads vmcnt-drain overlaps the next
//     load stream; one barrier per iteration; pk/pb/conv_w staged in LDS once.

static __device__ __forceinline__ float gelu_erf(float x) {
    return 0.5f * x * (1.0f + erff(x * 0.70710678118654752f));
}

__global__ __launch_bounds__(256) void mlp_precompute(
    const float* __restrict__ w1k, const float* __restrict__ b1k,
    const float* __restrict__ w2k, const float* __restrict__ b2k,
    const float* __restrict__ w1b, const float* __restrict__ b1b,
    const float* __restrict__ w2b, const float* __restrict__ b2b,
    float* __restrict__ pk_out,   // [L][64]
    float* __restrict__ pb_out)   // [L]
{
    constexpr int HID = 64;
    const int tid = threadIdx.x;
    const int pi  = tid >> 6;
    const int j   = tid & 63;
    const int l   = blockIdx.x * 4 + pi;

    const int py_i = l >> 6;
    const int px_i = l & 63;
    const float py = (float)(py_i * 8) + 4.0f - 256.0f;
    const float px = (float)(px_i * 8) + 4.0f - 256.0f;
    const float dd = sqrtf(py * py + px * px) * (1.0f / 362.03867196751236f);

    __shared__ float gk[4][HID];
    __shared__ float gb[4][HID];

    gk[pi][j] = gelu_erf(dd * w1k[j] + b1k[j]);
    gb[pi][j] = gelu_erf(dd * w1b[j] + b1b[j]);
    __syncthreads();

    float s = b2k[j];
#pragma unroll 8
    for (int h = 0; h < HID; ++h)
        s += gk[pi][h] * w2k[h * HID + j];
    pk_out[l * HID + j] = s;

    if (j == 0) {
        float t = b2b[0];
        for (int h = 0; h < HID; ++h)
            t += gb[pi][h] * w2b[h];
        pb_out[l] = t;
    }
}

__global__ __launch_bounds__(512, 4) void afpm_main(
    const float* __restrict__ x,
    const float* __restrict__ conv_w, const float* __restrict__ conv_b,
    const float* __restrict__ pk_g,   // [L][64]
    const float* __restrict__ pb_g,   // [L]
    float* __restrict__ out)
{
    constexpr int W   = 512;
    constexpr int PKS = 68;   // padded pk row stride (avoids pw-collapse bank conflicts)

    const int tid = threadIdx.x;
    const int q   = tid & 1;          // column half
    const int pw  = (tid >> 1) & 3;   // patch within group
    const int c   = tid >> 3;         // channel
    const int b   = blockIdx.x >> 6;  // batch
    const int ph  = blockIdx.x & 63;  // patch row

    __shared__ float convT[64 * 64];               // [cc][o] transposed 1x1-conv weights
    __shared__ __align__(16) float pkAll[64 * PKS];// [patch-col l][k], padded
    __shared__ float pbAll[64];
    __shared__ float rowsumL[64];
    __shared__ float f0L[2][64][4];                // parity-double-buffered feats

    // base address of this thread's (channel, row-band, patch/col-half), group 0
    const size_t cbase = (((size_t)b * 64 + c) * 512 + (size_t)ph * 8) * (size_t)W
                         + (size_t)(pw * 8 + q * 4);

    // ---- issue first pixel loads (group 0) before staging ----
    float4 vA[8], vB[8];
    {
        const float* xp = x + cbase;
#pragma unroll
        for (int r = 0; r < 8; ++r)
            vA[r] = *(const float4*)(xp + r * W);
    }

    // ---- one-time LDS staging: convT (transposed), pkAll (this ph-row), pbAll ----
    {
        const float4* cw4 = (const float4*)conv_w;          // 1024 float4
        const float4  w0  = cw4[tid * 2 + 0];
        const float4  w1  = cw4[tid * 2 + 1];
        const int o   = tid >> 3;
        const int cc0 = (tid & 7) * 8;
        convT[(cc0 + 0) * 64 + o] = w0.x; convT[(cc0 + 1) * 64 + o] = w0.y;
        convT[(cc0 + 2) * 64 + o] = w0.z; convT[(cc0 + 3) * 64 + o] = w0.w;
        convT[(cc0 + 4) * 64 + o] = w1.x; convT[(cc0 + 5) * 64 + o] = w1.y;
        convT[(cc0 + 6) * 64 + o] = w1.z; convT[(cc0 + 7) * 64 + o] = w1.w;

        const float4* pk4 = (const float4*)(pk_g + (size_t)(ph * 64) * 64); // 1024 f4
        const float4  k0  = pk4[tid * 2 + 0];
        const float4  k1  = pk4[tid * 2 + 1];
        const int l  = tid >> 3;
        const int kk = (tid & 7) * 8;
        *(float4*)&pkAll[l * PKS + kk + 0] = k0;
        *(float4*)&pkAll[l * PKS + kk + 4] = k1;

        if (tid < 64) pbAll[tid] = pb_g[ph * 64 + tid];
    }
    __syncthreads();

    // conv row sums (for the algebraic pb fold); visible after iter-0's barrier
    if (tid < 64) {
        float s = 0.0f;
#pragma unroll 8
        for (int cc = 0; cc < 64; ++cc) s += convT[cc * 64 + tid];
        rowsumL[tid] = s;
    }

    const float cb = conv_b[c];

    // ---- pipelined main loop: 16 patch-groups, one barrier per group ----
#define STEP(G, VC, VN, PRE, PAR)                                           \
    {                                                                       \
        if (PRE) {                                                          \
            const float* xn = x + cbase + ((G) + 1) * 32;                   \
            _Pragma("unroll")                                               \
            for (int r = 0; r < 8; ++r)                                     \
                VN[r] = *(const float4*)(xn + r * W);                       \
        }                                                                   \
        const int l = (G) * 4 + pw;                                         \
        const float* pkp = &pkAll[l * PKS + q * 4];                         \
        float s = 0.0f;                                                     \
        _Pragma("unroll")                                                   \
        for (int r = 0; r < 8; ++r) {                                       \
            const float4 a  = VC[r];                                        \
            const float4 kv = *(const float4*)(pkp + r * 8);                \
            s += a.x * kv.x + a.y * kv.y + a.z * kv.z + a.w * kv.w;         \
        }                                                                   \
        s += __shfl_xor(s, 1);                                              \
        if (q == 0) f0L[PAR][c][pw] = s;                                    \
        __syncthreads();                                                    \
        float t = 0.0f;                                                     \
        _Pragma("unroll 8")                                                 \
        for (int i = 0; i < 32; ++i) {                                      \
            const int cc = q * 32 + i;                                      \
            t += convT[cc * 64 + c] * f0L[PAR][cc][pw];                     \
        }                                                                   \
        t += __shfl_xor(t, 1);                                              \
        const float m = t + cb + pbAll[l] * rowsumL[c];                     \
        float* op = out + cbase + (G) * 32;                                 \
        _Pragma("unroll")                                                   \
        for (int r = 0; r < 8; ++r) {                                       \
            float4 a = VC[r];                                               \
            a.x *= m; a.y *= m; a.z *= m; a.w *= m;                         \
            *(float4*)(op + r * W) = a;                                     \
        }                                                                   \
    }

    for (int g = 0; g < 16; g += 2) {
        STEP(g,     vA, vB, true,            0);
        STEP(g + 1, vB, vA, ((g + 1) < 15),  1);
    }
#undef STEP
}

extern "C" void kernel_launch(void* const* d_in, const int* in_sizes, int n_in,
                              void* d_out, int out_size, void* d_ws, size_t ws_size,
                              hipStream_t stream) {
    const float* x      = (const float*)d_in[0];
    const float* w1k    = (const float*)d_in[1];
    const float* b1k    = (const float*)d_in[2];
    const float* w2k    = (const float*)d_in[3];
    const float* b2k    = (const float*)d_in[4];
    const float* w1b    = (const float*)d_in[5];
    const float* b1b    = (const float*)d_in[6];
    const float* w2b    = (const float*)d_in[7];
    const float* b2b    = (const float*)d_in[8];
    const float* conv_w = (const float*)d_in[9];
    const float* conv_b = (const float*)d_in[10];
    float* out = (float*)d_out;

    constexpr int L = 64 * 64;
    float* pk = (float*)d_ws;            // L*64 floats = 1 MiB
    float* pb = pk + (size_t)L * 64;     // L floats

    mlp_precompute<<<L / 4, 256, 0, stream>>>(w1k, b1k, w2k, b2k,
                                              w1b, b1b, w2b, b2b, pk, pb);

    // persistent: 512 blocks = (b:8 x ph:64), 2 blocks/CU
    afpm_main<<<512, 512, 0, stream>>>(x, conv_w, conv_b, pk, pb, out);
}

// Round 5
// 234.551 us; speedup vs baseline: 1.1209x; 1.1209x over previous
//
#include <hip/hip_runtime.h>
#include <math.h>

// B=8, C=64, H=512, W=512, K=8, HID=64, nh=nw=64, L=4096
//
//  A) mlp_precompute: pk[L][64], pb[L] into d_ws (runs once, ~8 us).
//  B) afpm_main: 8192 blocks x 512 threads = (c:64, pw:4, q:2); thread owns
//     half a patch (8 rows x 4 cols) = 8 float4. ONE barrier per block:
//       - pk read directly from global (L2-resident, no staging barrier)
//       - pb folded into the f0 LDS write
//       - conv done per-thread (q-split over 32 channels) + __shfl_xor,
//         removing the ft round-trip and its barrier
//     conv_w staged transposed in LDS (pad 65 -> <=2-way bank aliasing, free);
//     f0 padded to 68. All 512 threads active in every phase.

static __device__ __forceinline__ float gelu_erf(float x) {
    return 0.5f * x * (1.0f + erff(x * 0.70710678118654752f));
}

__global__ __launch_bounds__(256) void mlp_precompute(
    const float* __restrict__ w1k, const float* __restrict__ b1k,
    const float* __restrict__ w2k, const float* __restrict__ b2k,
    const float* __restrict__ w1b, const float* __restrict__ b1b,
    const float* __restrict__ w2b, const float* __restrict__ b2b,
    float* __restrict__ pk_out,   // [L][64]
    float* __restrict__ pb_out)   // [L]
{
    constexpr int HID = 64;
    const int tid = threadIdx.x;
    const int pi  = tid >> 6;
    const int j   = tid & 63;
    const int l   = blockIdx.x * 4 + pi;

    const int py_i = l >> 6;
    const int px_i = l & 63;
    const float py = (float)(py_i * 8) + 4.0f - 256.0f;
    const float px = (float)(px_i * 8) + 4.0f - 256.0f;
    const float dd = sqrtf(py * py + px * px) * (1.0f / 362.03867196751236f);

    __shared__ float gk[4][HID];
    __shared__ float gb[4][HID];

    gk[pi][j] = gelu_erf(dd * w1k[j] + b1k[j]);
    gb[pi][j] = gelu_erf(dd * w1b[j] + b1b[j]);
    __syncthreads();

    float s = b2k[j];
#pragma unroll 8
    for (int h = 0; h < HID; ++h)
        s += gk[pi][h] * w2k[h * HID + j];
    pk_out[l * HID + j] = s;

    if (j == 0) {
        float t = b2b[0];
        for (int h = 0; h < HID; ++h)
            t += gb[pi][h] * w2b[h];
        pb_out[l] = t;
    }
}

__global__ __launch_bounds__(512, 4) void afpm_main(
    const float* __restrict__ x,
    const float* __restrict__ conv_w, const float* __restrict__ conv_b,
    const float* __restrict__ pk_g,   // [L][64]
    const float* __restrict__ pb_g,   // [L]
    float* __restrict__ out)
{
    constexpr int W = 512;

    const int tid = threadIdx.x;
    const int q   = tid & 1;          // column half (cols q*4..q*4+3)
    const int pw  = (tid >> 1) & 3;   // patch within group
    const int c   = tid >> 3;         // channel
    const int pwg = blockIdx.x;       // 0..15
    const int ph  = blockIdx.y;       // 0..63
    const int b   = blockIdx.z;       // 0..7

    __shared__ float convT[64 * 65];  // [cc][o], pad 65
    __shared__ float f0T[4][68];      // [pw][cc], pad 68 (272B rows, 16B aligned)

    const int l = ph * 64 + pwg * 4 + pw;   // global patch index

    // ---- issue all loads up front (x pixels, pk row, conv_w, pb, conv_b) ----
    const size_t cbase = (((size_t)b * 64 + c) * 512 + (size_t)ph * 8) * (size_t)W
                         + (size_t)(pwg * 32 + pw * 8 + q * 4);
    const float* xp = x + cbase;
    float4 v[8];
#pragma unroll
    for (int r = 0; r < 8; ++r)
        v[r] = *(const float4*)(xp + r * W);

    // pk fragment for this (l, q): elements r*8+q*4 .. +3  -> f4 index l*16 + r*2 + q
    const float4* pkp = (const float4*)pk_g + (size_t)l * 16 + q;
    float4 kv[8];
#pragma unroll
    for (int r = 0; r < 8; ++r)
        kv[r] = pkp[r * 2];

    const float pbv = pb_g[l];
    const float cbv = conv_b[c];

    // ---- stage conv_w transposed into LDS (pad 65 -> conflict-light) ----
    {
        const float4* cw4 = (const float4*)conv_w;      // 1024 float4
        const float4 w0 = cw4[tid * 2 + 0];
        const float4 w1 = cw4[tid * 2 + 1];
        const int o   = tid >> 3;
        const int cc0 = (tid & 7) * 8;
        convT[(cc0 + 0) * 65 + o] = w0.x; convT[(cc0 + 1) * 65 + o] = w0.y;
        convT[(cc0 + 2) * 65 + o] = w0.z; convT[(cc0 + 3) * 65 + o] = w0.w;
        convT[(cc0 + 4) * 65 + o] = w1.x; convT[(cc0 + 5) * 65 + o] = w1.y;
        convT[(cc0 + 6) * 65 + o] = w1.z; convT[(cc0 + 7) * 65 + o] = w1.w;
    }

    // ---- dot(patch-half, pk-half) ----
    float s = 0.0f;
#pragma unroll
    for (int r = 0; r < 8; ++r) {
        s += v[r].x * kv[r].x + v[r].y * kv[r].y
           + v[r].z * kv[r].z + v[r].w * kv[r].w;
    }
    s += __shfl_xor(s, 1);            // combine column halves
    if (q == 0)
        f0T[pw][c] = s + pbv;         // pb folded here

    __syncthreads();                  // the ONE barrier

    // ---- per-thread 1x1 conv, q-split over input channels ----
    const float* f0p = &f0T[pw][q * 32];
    float t = 0.0f;
#pragma unroll
    for (int i4 = 0; i4 < 8; ++i4) {
        const float4 f = *(const float4*)(f0p + i4 * 4);
        const int ccb = q * 32 + i4 * 4;
        t += convT[(ccb + 0) * 65 + c] * f.x
           + convT[(ccb + 1) * 65 + c] * f.y
           + convT[(ccb + 2) * 65 + c] * f.z
           + convT[(ccb + 3) * 65 + c] * f.w;
    }
    t += __shfl_xor(t, 1);            // combine the two cc-halves
    const float m = t + cbv;

    // ---- modulate + store ----
    float* op = out + cbase;
#pragma unroll
    for (int r = 0; r < 8; ++r) {
        float4 a = v[r];
        a.x *= m; a.y *= m; a.z *= m; a.w *= m;
        *(float4*)(op + r * W) = a;
    }
}

extern "C" void kernel_launch(void* const* d_in, const int* in_sizes, int n_in,
                              void* d_out, int out_size, void* d_ws, size_t ws_size,
                              hipStream_t stream) {
    const float* x      = (const float*)d_in[0];
    const float* w1k    = (const float*)d_in[1];
    const float* b1k    = (const float*)d_in[2];
    const float* w2k    = (const float*)d_in[3];
    const float* b2k    = (const float*)d_in[4];
    const float* w1b    = (const float*)d_in[5];
    const float* b1b    = (const float*)d_in[6];
    const float* w2b    = (const float*)d_in[7];
    const float* b2b    = (const float*)d_in[8];
    const float* conv_w = (const float*)d_in[9];
    const float* conv_b = (const float*)d_in[10];
    float* out = (float*)d_out;

    constexpr int L = 64 * 64;
    float* pk = (float*)d_ws;            // L*64 floats = 1 MiB
    float* pb = pk + (size_t)L * 64;     // L floats

    mlp_precompute<<<L / 4, 256, 0, stream>>>(w1k, b1k, w2k, b2k,
                                              w1b, b1b, w2b, b2b, pk, pb);

    dim3 grid(16, 64, 8);
    afpm_main<<<grid, 512, 0, stream>>>(x, conv_w, conv_b, pk, pb, out);
}